// Round 13
// baseline (3961.880 us; speedup 1.0000x reference)
//
#include <hip/hip_runtime.h>
#include <stdint.h>

// ---------------------------------------------------------------------------
// LstmAtt round 20: r19 champion base (3746us) + gates 2-ktile phases.
//  - gates: BM=128 x BN=96, BK=64, grid 256 x 512 thr (8 waves 4Mx2N).
//    NEW: two ktiles per pipeline phase — 2 buffers x 57KB (112KB LDS,
//    free at 1 block/CU), barrier pairs 19 -> 10, per-phase 24 MFMA +
//    20 ds_read per wave (k1 ds_reads overlap k0 MFMAs, no barrier
//    between). Counted vmcnt(8)/(6) steady, (4)/(3) before the 1-ktile
//    tail phase, (0) last. XCD swizzle unchanged.
//  - softmax_v (MFMA v-product) / logits (split-K4, 768 blk) / final_head
//    / packs: r19 EXACT.
// Act row layout (KPAD=1216 halfs): [0..389]=v, [390..415]=0, [416..1183]=h,
// [1184..1215]=0 pad.
// Error ledger: zero arithmetic change vs r19; absmax expected 9.765e-4
// exactly (thr 3.96e-3).
// ---------------------------------------------------------------------------

#define B_SZ   1024
#define LSEQ   128
#define DIN    130
#define HDIM   768
#define NFEAT  49
#define NPROJ  40
#define KPAD   1216
#define VOFF   416
#define NGATE  3072
#define KT_G   19       // KPAD/64
#define PH_G   10       // pipeline phases (2 ktiles each; last has 1)
#define XELEM  (LSEQ * DIN)   // 16640
#define GBUF   28672    // bytes per ktile stage (A 16KB + B 12KB)

typedef unsigned short u16;
typedef __attribute__((ext_vector_type(8))) short short8;
typedef __attribute__((ext_vector_type(4))) float f32x4;

__device__ __forceinline__ u16 f2bf(float f) {
  unsigned int u = __float_as_uint(f);
  u += 0x7FFFu + ((u >> 16) & 1u);
  return (u16)(u >> 16);
}
__device__ __forceinline__ float bf2f(u16 b) {
  return __uint_as_float(((unsigned int)b) << 16);
}
__device__ __forceinline__ float frcp(float x) {
  return __builtin_amdgcn_rcpf(x);
}
// tanh(x) = 1 - 2/(e^{2x}+1); exp overflow -> inf -> rcp 0 -> 1 (correct).
__device__ __forceinline__ float ftanh(float x) {
  return 1.f - 2.f * frcp(1.f + __expf(2.f * x));
}
__device__ __forceinline__ float fsigm(float x) {
  return frcp(1.f + __expf(-x));
}
__device__ __forceinline__ void gload16(const void* g, void* l) {
  __builtin_amdgcn_global_load_lds(
      (__attribute__((address_space(1))) const void*)g,
      (__attribute__((address_space(3))) void*)l, 16, 0, 0);
}

// ---------------------------------------------------------------------------
// Logits GEMM, split-K=4: Cpart[kh][1024,384] = h[1024, kh-quarter of 768]
// @ W^T. BM=32, BN=64, 256 thr (waves 2x2: wave tile 16x32), 6 ktiles.
// Grid (32,6,4) = 768 blocks = 3.0/CU balanced.
// ---------------------------------------------------------------------------
__global__ __launch_bounds__(256, 4) void gemm_logits_k(
    const u16* __restrict__ Ah,
    const u16* __restrict__ Bh, float* __restrict__ Cp)
{
  __shared__ __align__(16) u16 sAh[32 * 40];
  __shared__ __align__(16) u16 sBh[64 * 40];

  const int tid = threadIdx.x, lane = tid & 63, wid = tid >> 6;
  const int wm = (wid & 1) * 16, wn = (wid >> 1) * 32;
  const int lm = lane & 15, quad = lane >> 4;
  const int bm = blockIdx.x * 32, bn = blockIdx.y * 64;
  const int kh = blockIdx.z;             // 0..3
  const int kbase = kh * 192;            // halfs
  float* __restrict__ C = Cp + (size_t)kh * B_SZ * 384;

  const bool aload = tid < 128;
  const int ar = tid >> 2, ac = (tid & 3) * 8;
  const size_t a_off = (size_t)(bm + ar) * KPAD + kbase + ac;
  const size_t b_off = (size_t)(bn + ar) * HDIM + kbase + ac;

  uint4 ph, pb;
  if (aload) ph = *(const uint4*)(Ah + a_off);
  pb = *(const uint4*)(Bh + b_off);

  f32x4 acc0 = {0.f, 0.f, 0.f, 0.f}, acc1 = {0.f, 0.f, 0.f, 0.f};

  for (int kt = 0; kt < 6; ++kt) {
    if (aload) *(uint4*)&sAh[ar * 40 + ac] = ph;
    *(uint4*)&sBh[ar * 40 + ac] = pb;
    __syncthreads();
    if (kt + 1 < 6) {
      const int k0 = (kt + 1) * 32;
      if (aload) ph = *(const uint4*)(Ah + a_off + k0);
      pb = *(const uint4*)(Bh + b_off + k0);
    }
    const short8 ah = *(const short8*)&sAh[(wm + lm) * 40 + quad * 8];
    const short8 b0 = *(const short8*)&sBh[(wn + lm) * 40 + quad * 8];
    const short8 b1 = *(const short8*)&sBh[(wn + 16 + lm) * 40 + quad * 8];
    acc0 = __builtin_amdgcn_mfma_f32_16x16x32_bf16(ah, b0, acc0, 0, 0, 0);
    acc1 = __builtin_amdgcn_mfma_f32_16x16x32_bf16(ah, b1, acc1, 0, 0, 0);
    __syncthreads();
  }

  const int col = bn + wn + lm;
  const int row0 = bm + wm + quad * 4;
#pragma unroll
  for (int r = 0; r < 4; ++r) {
    C[(size_t)(row0 + r) * 384 + col]      = acc0[r];
    C[(size_t)(row0 + r) * 384 + col + 16] = acc1[r];
  }
}

// ---------------------------------------------------------------------------
// Gates GEMM + fused LSTM. BM=128 x BN=96 (4 gate-strips of 24 j), BK=64.
// 512 thr, 8 waves 4(M)x2(N): wave tile 32x48 (FM=2, FN=3).
// Pipeline: 10 phases of 2 ktiles (last = 1); 2 buffers x 57344 B = 112KB
// LDS (free at 1 block/CU). Per phase per thread: 8 loads (waves 0-3) / 6
// (waves 4-7); counted vmcnt(8)/(6) steady, (4)/(3) before tail, (0) last;
// raw s_barrier pair per PHASE (10 pairs, was 19).
// Grid 256 = 1 block/CU of 8 waves. XCD swizzle: 8 bm x 4 js per XCD.
// ---------------------------------------------------------------------------
__global__ __launch_bounds__(512, 2) void gates_lstm(
    const u16* __restrict__ Ah,   // act rd [B][KPAD]
    const u16* __restrict__ Wh,   // wcat [3072][KPAD], rows = gate*768+j
    const float* __restrict__ bsum,
    float* __restrict__ cst, float* __restrict__ hmax,
    u16* __restrict__ out_h)      // act wr (h section written)
{
  __shared__ __align__(16) char smem[4 * GBUF];   // 114688 B (2 x 2-ktile buf)

  const int tid = threadIdx.x, lane = tid & 63, wid = tid >> 6;
  const int wm = (wid >> 1) * 32, wn = (wid & 1) * 48;
  const int lm = lane & 15, quad = lane >> 4;

  // XCD-chunked block swizzle (256 = 8 XCD * 32).
  const int wg = blockIdx.x;
  const int vid = (wg & 7) * 32 + (wg >> 3);
  const int bm = (vid & 7) * 128;         // sample strip (8 strips)
  const int j0 = (vid >> 3) * 24;         // j strip (32 strips of 24)

  // --- staging source pointers (per-lane, swizzle folded into column) ---
  const u16* Asrc[2];
#pragma unroll
  for (int i = 0; i < 2; ++i) {
    const int r = i * 64 + (tid >> 3);
    const int s = (tid & 7) ^ (r & 7);
    Asrc[i] = Ah + (size_t)(bm + r) * KPAD + (s << 3);
  }
  const u16* Bsrc0;
  const u16* Bsrc1;
  {
    const int r0 = tid >> 3;
    const int s0 = (tid & 7) ^ (r0 & 7);
    const int nrow0 = (r0 / 24) * HDIM + j0 + (r0 % 24);
    Bsrc0 = Wh + (size_t)nrow0 * KPAD + (s0 << 3);
    const int r1 = 64 + (tid >> 3);
    const int s1 = (tid & 7) ^ (r1 & 7);
    const int r1c = (r1 < 96) ? r1 : 95;               // clamp (unused lanes)
    const int nrow1 = (r1c / 24) * HDIM + j0 + (r1c % 24);
    Bsrc1 = Wh + (size_t)nrow1 * KPAD + (s1 << 3);
  }

  // --- ds_read fragment offsets (halfs); kk toggles slot bit 2 (half-bit 5)
  int aoff[2], boff[3];
#pragma unroll
  for (int mi = 0; mi < 2; ++mi) {
    const int R = wm + mi * 16 + lm;
    aoff[mi] = R * 64 + ((quad ^ (R & 7)) << 3);
  }
#pragma unroll
  for (int ni = 0; ni < 3; ++ni) {
    const int R = wn + ni * 16 + lm;
    boff[ni] = R * 64 + ((quad ^ (R & 7)) << 3);
  }

  f32x4 acc[2][3];
#pragma unroll
  for (int mi = 0; mi < 2; ++mi)
#pragma unroll
    for (int ni = 0; ni < 3; ++ni) acc[mi][ni] = (f32x4){0.f, 0.f, 0.f, 0.f};

  // stage one PHASE (2 ktiles; tail phase 9 has 1) into buffer buf.
  auto stage = [&](int buf, int ph) {
    char* bb = smem + buf * (2 * GBUF);
    const int nk = (ph == PH_G - 1) ? 1 : 2;
    for (int sub = 0; sub < nk; ++sub) {
      char* tb = bb + sub * GBUF;
      const int k0 = (2 * ph + sub) * 64;          // halfs
      gload16(Asrc[0] + k0, tb + (tid << 4));            // A rows 0..63
      gload16(Asrc[1] + k0, tb + 8192 + (tid << 4));     // A rows 64..127
      gload16(Bsrc0 + k0, tb + 16384 + (tid << 4));      // B rows 0..63
      if (tid < 256)
        gload16(Bsrc1 + k0, tb + 24576 + (tid << 4));    // B rows 64..95
    }
  };

  stage(0, 0);                            // 8/6 loads per thread in flight

  for (int ph = 0; ph < PH_G; ++ph) {
    if (ph + 1 < PH_G) {
      stage((ph + 1) & 1, ph + 1);
      if (ph + 1 == PH_G - 1) {           // staged 1-ktile tail: 4/3 out
        if (wid < 4) asm volatile("s_waitcnt vmcnt(4)" ::: "memory");
        else         asm volatile("s_waitcnt vmcnt(3)" ::: "memory");
      } else {                            // staged full pair: 8/6 out
        if (wid < 4) asm volatile("s_waitcnt vmcnt(8)" ::: "memory");
        else         asm volatile("s_waitcnt vmcnt(6)" ::: "memory");
      }
    } else {
      asm volatile("s_waitcnt vmcnt(0)" ::: "memory");
    }
    asm volatile("s_barrier" ::: "memory");   // all waves' buffer ready

    const char* bb = smem + (ph & 1) * (2 * GBUF);
    const int nk = (ph == PH_G - 1) ? 1 : 2;
    for (int sub = 0; sub < nk; ++sub) {
      const u16* sA = (const u16*)(bb + sub * GBUF);
      const u16* sB = sA + 8192;          // A is 128x64 halfs = 16KB
#pragma unroll
      for (int kk = 0; kk < 2; ++kk) {
        const int kx = kk << 5;           // toggle half-bit 5 = slot bit 2
        short8 af[2], bg[3];
#pragma unroll
        for (int mi = 0; mi < 2; ++mi)
          af[mi] = *(const short8*)(sA + (aoff[mi] ^ kx));
#pragma unroll
        for (int ni = 0; ni < 3; ++ni)
          bg[ni] = *(const short8*)(sB + (boff[ni] ^ kx));
#pragma unroll
        for (int mi = 0; mi < 2; ++mi)
#pragma unroll
          for (int ni = 0; ni < 3; ++ni)
            acc[mi][ni] = __builtin_amdgcn_mfma_f32_16x16x32_bf16(
                af[mi], bg[ni], acc[mi][ni], 0, 0, 0);
      }
    }
    asm volatile("s_barrier" ::: "memory");   // reads of this buffer done
  }

  // ---- epilogue: acc -> 128x100 fp32 LDS tile (col = gate*24 + jj) ----
  float* tile = (float*)smem;               // 51200 B
#pragma unroll
  for (int mi = 0; mi < 2; ++mi)
#pragma unroll
    for (int ni = 0; ni < 3; ++ni) {
      const int c = wn + ni * 16 + lm;
#pragma unroll
      for (int r = 0; r < 4; ++r)
        tile[(wm + mi * 16 + quad * 4 + r) * 100 + c] = acc[mi][ni][r];
    }
  __syncthreads();

#pragma unroll
  for (int i = 0; i < 6; ++i) {
    const int lin = tid + 512 * i;        // 128 rows x 24 jj = 3072
    const int row = lin / 24, jj = lin - row * 24;
    const int b = bm + row, j = j0 + jj;
    const float* tr = tile + row * 100;
    const float pi = tr[jj]      + bsum[j];
    const float pf = tr[24 + jj] + bsum[HDIM + j];
    const float pg = tr[48 + jj] + bsum[2 * HDIM + j];
    const float po = tr[72 + jj] + bsum[3 * HDIM + j];
    const float si = fsigm(pi);
    const float sf = fsigm(pf);
    const float so = fsigm(po);
    const size_t cidx = (size_t)b * HDIM + j;
    const float cn = sf * cst[cidx] + si * ftanh(pg);
    const float hn = so * ftanh(cn);
    cst[cidx] = cn;
    hmax[cidx] = fmaxf(hmax[cidx], hn);
    out_h[(size_t)b * KPAD + VOFF + j] = f2bf(hn);
  }
}

// ---------------------------------------------------------------------------
// softmax_v: logits = sum of 4 split-K partials + b_att; wave-shuffle
// softmax (3 barriers); v = alp @ X via MFMA (9 d-tiles x 4 K-steps, one
// d-tile per wave, wave 0 takes tile 8). alp stored bf16; A rows 3-15 are
// zero fragments; B rows clamped to d=129 (unused lanes discarded).
// ---------------------------------------------------------------------------
__global__ __launch_bounds__(512, 4) void softmax_v(
    const float* __restrict__ lpart,     // [4][B][384]
    const float* __restrict__ b_att,
    const u16* __restrict__ XT,          // [B][130][128] bf16 (linear)
    u16* __restrict__ act)
{
  const int b = blockIdx.x;
  const int t = threadIdx.x;
  __shared__ __align__(16) u16 sXT[XELEM];   // swizzled [130][128]
  __shared__ __align__(16) u16 s_alpb[384];  // alp bf16 [3][128]
  __shared__ float s_w[16];

  {
    const uint4* src = (const uint4*)(XT + (size_t)b * XELEM);
    uint4* dst = (uint4*)sXT;
#pragma unroll
    for (int rep = 0; rep < 4; ++rep) {
      const int i = t + rep * 512;       // 0..2047
      const int d = i >> 4, blk = i & 15;
      dst[d * 16 + (blk ^ (d & 7))] = src[i];
    }
    if (t < 32) {
      const int i = 2048 + t;
      const int d = i >> 4, blk = i & 15;
      dst[d * 16 + (blk ^ (d & 7))] = src[i];
    }
  }

  const int lane = t & 63, wv = t >> 6, hw = wv & ~1;
  float x = -3.4e38f;
  if (t < 384) {
    const size_t str = (size_t)B_SZ * 384;
    const float* lp = lpart + (size_t)b * 384 + t;
    x = b_att[t] + ((lp[0] + lp[str]) + (lp[2 * str] + lp[3 * str]));
  }

  float m = x;
#pragma unroll
  for (int off = 32; off > 0; off >>= 1) m = fmaxf(m, __shfl_xor(m, off));
  if (lane == 0 && wv < 6) s_w[wv] = m;
  __syncthreads();

  float e = 0.f;
  if (t < 384) e = __expf(x - fmaxf(s_w[hw], s_w[hw | 1]));
  float sum = e;
#pragma unroll
  for (int off = 32; off > 0; off >>= 1) sum += __shfl_xor(sum, off);
  if (lane == 0 && wv < 6) s_w[8 + wv] = sum;
  __syncthreads();

  if (t < 384) {
    const float sk = s_w[8 + hw] + s_w[8 + (hw | 1)];
    s_alpb[t] = f2bf(e * frcp(sk));
  }
  __syncthreads();    // orders sXT staging + s_alpb for the v phase

  // ---- v = alp @ X via MFMA: wave wv does d-tile wv (+ tile 8 on wave 0) --
  {
    const int lmn = lane & 15, qd = lane >> 4;
    for (int tile = wv; tile < 9; tile += 8) {
      const int d0 = tile * 16;
      const int dr = (d0 + lmn < DIN) ? (d0 + lmn) : (DIN - 1);  // clamp B row
      f32x4 vacc = {0.f, 0.f, 0.f, 0.f};
#pragma unroll
      for (int kk = 0; kk < 4; ++kk) {
        short8 afr = (short8){0, 0, 0, 0, 0, 0, 0, 0};
        if (lmn < 3)
          afr = *(const short8*)&s_alpb[lmn * 128 + kk * 32 + qd * 8];
        const int ch = (kk * 4 + qd) ^ (dr & 7);
        const short8 bfr = *(const short8*)&sXT[(dr * 16 + ch) * 8];
        vacc = __builtin_amdgcn_mfma_f32_16x16x32_bf16(afr, bfr, vacc, 0, 0, 0);
      }
      if (qd == 0) {
        const int d = d0 + lmn;
        if (d < DIN) {
#pragma unroll
          for (int r = 0; r < 3; ++r)
            act[(size_t)b * KPAD + r * DIN + d] = f2bf(vacc[r]);
        }
      }
    }
  }
}

// ---------------------------------------------------------------------------
// Final head (once per call).
// ---------------------------------------------------------------------------
__global__ __launch_bounds__(64) void final_head(
    const float* __restrict__ hmax, const float* __restrict__ Fe,
    const float* __restrict__ W_d1, const float* __restrict__ b_d1,
    const float* __restrict__ W_r,  const float* __restrict__ b_r,
    const float* __restrict__ W_a,
    const float* __restrict__ W_d2, const float* __restrict__ b_d2,
    float* __restrict__ out)
{
  const int b = blockIdx.x;
  const int t = threadIdx.x;
  __shared__ float sx[HDIM];
  __shared__ float sy[NFEAT];
  __shared__ float sr1[NPROJ], sr2[NPROJ];
  __shared__ float sa[2];

  for (int i = t; i < HDIM; i += 64) sx[i] = hmax[(size_t)b * HDIM + i];
  __syncthreads();

  if (t < NFEAT) {
    float acc = b_d1[t];
    const float* w = W_d1 + (size_t)t * HDIM;
    for (int i = 0; i < HDIM; ++i) acc += sx[i] * w[i];
    sy[t] = fmaxf(acc, 0.f);
  }
  __syncthreads();

  if (t < NPROJ) {
    float a1 = b_r[t], a2 = b_r[t];
    const float* w  = W_r + (size_t)t * NFEAT;
    const float* fe = Fe + (size_t)b * NFEAT;
    for (int i = 0; i < NFEAT; ++i) { a1 += sy[i] * w[i]; a2 += fe[i] * w[i]; }
    sr1[t] = (a1 > 0.f) ? a1 : 0.01f * a1;
    sr2[t] = (a2 > 0.f) ? a2 : 0.01f * a2;
  }
  __syncthreads();

  if (t == 0) {
    float a1 = 0.f, a2 = 0.f;
    for (int p = 0; p < NPROJ; ++p) {
      a1 += tanhf(sr1[p]) * W_a[p];
      a2 += tanhf(sr2[p]) * W_a[p];
    }
    const float mx = fmaxf(a1, a2);
    const float e1 = expf(a1 - mx), e2 = expf(a2 - mx);
    sa[0] = e1 / (e1 + e2);
    sa[1] = e2 / (e1 + e2);
  }
  __syncthreads();

  if (t < 2) {
    float acc = b_d2[t];
    const float* w = W_d2 + (size_t)t * NPROJ;
    for (int p = 0; p < NPROJ; ++p) {
      float s = sa[0] * sr1[p] + sa[1] * sr2[p];
      s = fmaxf(s, 0.f);
      acc += s * w[p];
    }
    out[(size_t)b * 2 + t] = acc;
  }
}

// ---------------------------------------------------------------------------
// Setup kernels (run every launch).
// ---------------------------------------------------------------------------
__global__ __launch_bounds__(256) void pack_w(
    const float* __restrict__ W_ih, const float* __restrict__ W_hh,
    const float* __restrict__ b_ih, const float* __restrict__ b_hh,
    u16* __restrict__ hi, float* __restrict__ bsum)
{
  const int idx = blockIdx.x * 256 + threadIdx.x;
  if (idx >= NGATE * KPAD) return;
  const int n = idx / KPAD;
  const int k = idx - n * KPAD;
  float v = 0.f;
  if (k < 3 * DIN)                       v = W_ih[(size_t)n * (3 * DIN) + k];
  else if (k >= VOFF && k < VOFF + HDIM) v = W_hh[(size_t)n * HDIM + (k - VOFF)];
  hi[idx] = f2bf(v);
  if (k == 0) bsum[n] = b_ih[n] + b_hh[n];
}

__global__ __launch_bounds__(256) void pack_watt(
    const float* __restrict__ W_att,   // [3][H][L]
    u16* __restrict__ hi)
{
  const int idx = blockIdx.x * 256 + threadIdx.x;   // [384][768]
  if (idx >= 384 * HDIM) return;
  const int n = idx / HDIM;          // n = k*128 + l
  const int h = idx - n * HDIM;
  const int katt = n >> 7;
  const int l = n & 127;
  hi[idx] = f2bf(W_att[((size_t)katt * HDIM + h) * LSEQ + l]);
}

// X[b][l][d] fp32 -> XT[b][d][l] bf16 (linear). One block/sample, LDS bounce.
__global__ __launch_bounds__(256) void pack_xt(
    const float* __restrict__ X, u16* __restrict__ XT)
{
  const int b = blockIdx.x;
  const int t = threadIdx.x;
  __shared__ u16 sX[XELEM];   // [l][d]
  const float* src = X + (size_t)b * XELEM;
  for (int i = t; i < XELEM; i += 256) sX[i] = f2bf(src[i]);
  __syncthreads();
  uint4* dst = (uint4*)(XT + (size_t)b * XELEM);
  for (int u = t; u < 2080; u += 256) {    // uint4 index = d*16 + blk
    const int d = u >> 4, blk = u & 15;
    const int lb = blk * 8;
    ushort4 w0, w1;
    w0.x = sX[(lb + 0) * DIN + d]; w0.y = sX[(lb + 1) * DIN + d];
    w0.z = sX[(lb + 2) * DIN + d]; w0.w = sX[(lb + 3) * DIN + d];
    w1.x = sX[(lb + 4) * DIN + d]; w1.y = sX[(lb + 5) * DIN + d];
    w1.z = sX[(lb + 6) * DIN + d]; w1.w = sX[(lb + 7) * DIN + d];
    uint4 o;
    o.x = (unsigned)w0.x | ((unsigned)w0.y << 16);
    o.y = (unsigned)w0.z | ((unsigned)w0.w << 16);
    o.z = (unsigned)w1.x | ((unsigned)w1.y << 16);
    o.w = (unsigned)w1.z | ((unsigned)w1.w << 16);
    dst[u] = o;
  }
}

__global__ __launch_bounds__(256) void init_state(
    u16* __restrict__ a0, u16* __restrict__ a1,
    float* __restrict__ cst, float* __restrict__ hmax)
{
  const int idx = blockIdx.x * 256 + threadIdx.x;
  if (idx < B_SZ * KPAD) { a0[idx] = 0; a1[idx] = 0; }
  if (idx < B_SZ * HDIM) { cst[idx] = 0.f; hmax[idx] = -3.4e38f; }
}

// ---------------------------------------------------------------------------
extern "C" void kernel_launch(void* const* d_in, const int* in_sizes, int n_in,
                              void* d_out, int out_size, void* d_ws, size_t ws_size,
                              hipStream_t stream) {
  const float* X     = (const float*)d_in[0];
  const float* Fe    = (const float*)d_in[1];
  const float* W_att = (const float*)d_in[2];
  const float* b_att = (const float*)d_in[3];
  const float* W_ih  = (const float*)d_in[4];
  const float* W_hh  = (const float*)d_in[5];
  const float* b_ih  = (const float*)d_in[6];
  const float* b_hh  = (const float*)d_in[7];
  const float* W_d1  = (const float*)d_in[8];
  const float* b_d1  = (const float*)d_in[9];
  const float* W_r   = (const float*)d_in[10];
  const float* b_r   = (const float*)d_in[11];
  const float* W_a   = (const float*)d_in[12];
  const float* W_d2  = (const float*)d_in[13];
  const float* b_d2  = (const float*)d_in[14];
  float* out = (float*)d_out;

  char* base = (char*)d_ws;
  size_t off = 0;
  auto alloc = [&](size_t nbytes) -> void* {
    void* p = base + off;
    off = (off + nbytes + 255) & ~(size_t)255;
    return p;
  };
  u16* act0    = (u16*)alloc((size_t)B_SZ * KPAD * 2);
  u16* act1    = (u16*)alloc((size_t)B_SZ * KPAD * 2);
  u16* wcat    = (u16*)alloc((size_t)NGATE * KPAD * 2);
  u16* watt    = (u16*)alloc((size_t)384 * HDIM * 2);
  u16* xt16    = (u16*)alloc((size_t)B_SZ * XELEM * 2);
  float* bsum  = (float*)alloc((size_t)NGATE * 4);
  float* lpart = (float*)alloc((size_t)4 * B_SZ * 384 * 4);
  float* cst   = (float*)alloc((size_t)B_SZ * HDIM * 4);
  float* hmax  = (float*)alloc((size_t)B_SZ * HDIM * 4);

  pack_w<<<(NGATE * KPAD + 255) / 256, 256, 0, stream>>>(W_ih, W_hh, b_ih, b_hh, wcat, bsum);
  pack_watt<<<(384 * HDIM + 255) / 256, 256, 0, stream>>>(W_att, watt);
  pack_xt<<<B_SZ, 256, 0, stream>>>(X, xt16);
  init_state<<<(B_SZ * KPAD + 255) / 256, 256, 0, stream>>>(act0, act1, cst, hmax);

  // step-0 attention on h=0 (logits = b_att): partials from zero h are zero
  gemm_logits_k<<<dim3(B_SZ / 32, 384 / 64, 4), 256, 0, stream>>>(act0 + VOFF, watt, lpart);
  softmax_v<<<B_SZ, 512, 0, stream>>>(lpart, b_att, xt16, act0);

  u16 *rd = act0, *wr = act1;
  for (int step = 0; step < LSEQ; ++step) {
    gates_lstm<<<dim3(256), 512, 0, stream>>>(rd, wcat, bsum, cst, hmax, wr);
    if (step + 1 < LSEQ) {
      gemm_logits_k<<<dim3(B_SZ / 32, 384 / 64, 4), 256, 0, stream>>>(wr + VOFF, watt, lpart);
      softmax_v<<<B_SZ, 512, 0, stream>>>(lpart, b_att, xt16, wr);
    }
    u16* tt = rd; rd = wr; wr = tt;
  }

  final_head<<<B_SZ, 64, 0, stream>>>(hmax, Fe, W_d1, b_d1, W_r, b_r, W_a, W_d2, b_d2, out);
}

// Round 14
// 3700.542 us; speedup vs baseline: 1.0706x; 1.0706x over previous
//
#include <hip/hip_runtime.h>
#include <stdint.h>

// ---------------------------------------------------------------------------
// LstmAtt round 21: r19 champion verbatim (3746us measured).
//  - gates: BM=128 x BN=96, BK=64, grid 256 x 512 thr (8 waves 4Mx2N),
//    2-buffer dbuf, counted vmcnt(4)/(3)/(0), raw s_barrier pair per ktile,
//    XCD swizzle. [r16 K-split, r17 3-buf, r20 2-ktile phases all probed:
//    null/regress — this structure is the measured local optimum.]
//  - logits: split-K=4, BM=32 x BN=64, grid (32,6,4)=768 = 3.0/CU balanced.
//  - softmax_v: wave-shuffle softmax + MFMA v-product (9 d-tiles, m89
//    C-layout), alp bf16 pre-rounded.
//  - final_head / packs unchanged.
// Act row layout (KPAD=1216 halfs): [0..389]=v, [390..415]=0, [416..1183]=h,
// [1184..1215]=0 pad.
// Error ledger: absmax 9.765e-4 measured (thr 3.96e-3).
// ---------------------------------------------------------------------------

#define B_SZ   1024
#define LSEQ   128
#define DIN    130
#define HDIM   768
#define NFEAT  49
#define NPROJ  40
#define KPAD   1216
#define VOFF   416
#define NGATE  3072
#define KT_G   19       // KPAD/64
#define XELEM  (LSEQ * DIN)   // 16640
#define GBUF   28672    // bytes per LDS stage buffer (A 16KB + B 12KB)

typedef unsigned short u16;
typedef __attribute__((ext_vector_type(8))) short short8;
typedef __attribute__((ext_vector_type(4))) float f32x4;

__device__ __forceinline__ u16 f2bf(float f) {
  unsigned int u = __float_as_uint(f);
  u += 0x7FFFu + ((u >> 16) & 1u);
  return (u16)(u >> 16);
}
__device__ __forceinline__ float bf2f(u16 b) {
  return __uint_as_float(((unsigned int)b) << 16);
}
__device__ __forceinline__ float frcp(float x) {
  return __builtin_amdgcn_rcpf(x);
}
// tanh(x) = 1 - 2/(e^{2x}+1); exp overflow -> inf -> rcp 0 -> 1 (correct).
__device__ __forceinline__ float ftanh(float x) {
  return 1.f - 2.f * frcp(1.f + __expf(2.f * x));
}
__device__ __forceinline__ float fsigm(float x) {
  return frcp(1.f + __expf(-x));
}
__device__ __forceinline__ void gload16(const void* g, void* l) {
  __builtin_amdgcn_global_load_lds(
      (__attribute__((address_space(1))) const void*)g,
      (__attribute__((address_space(3))) void*)l, 16, 0, 0);
}

// ---------------------------------------------------------------------------
// Logits GEMM, split-K=4: Cpart[kh][1024,384] = h[1024, kh-quarter of 768]
// @ W^T. BM=32, BN=64, 256 thr (waves 2x2: wave tile 16x32), 6 ktiles.
// Grid (32,6,4) = 768 blocks = 3.0/CU balanced.
// ---------------------------------------------------------------------------
__global__ __launch_bounds__(256, 4) void gemm_logits_k(
    const u16* __restrict__ Ah,
    const u16* __restrict__ Bh, float* __restrict__ Cp)
{
  __shared__ __align__(16) u16 sAh[32 * 40];
  __shared__ __align__(16) u16 sBh[64 * 40];

  const int tid = threadIdx.x, lane = tid & 63, wid = tid >> 6;
  const int wm = (wid & 1) * 16, wn = (wid >> 1) * 32;
  const int lm = lane & 15, quad = lane >> 4;
  const int bm = blockIdx.x * 32, bn = blockIdx.y * 64;
  const int kh = blockIdx.z;             // 0..3
  const int kbase = kh * 192;            // halfs
  float* __restrict__ C = Cp + (size_t)kh * B_SZ * 384;

  const bool aload = tid < 128;
  const int ar = tid >> 2, ac = (tid & 3) * 8;
  const size_t a_off = (size_t)(bm + ar) * KPAD + kbase + ac;
  const size_t b_off = (size_t)(bn + ar) * HDIM + kbase + ac;

  uint4 ph, pb;
  if (aload) ph = *(const uint4*)(Ah + a_off);
  pb = *(const uint4*)(Bh + b_off);

  f32x4 acc0 = {0.f, 0.f, 0.f, 0.f}, acc1 = {0.f, 0.f, 0.f, 0.f};

  for (int kt = 0; kt < 6; ++kt) {
    if (aload) *(uint4*)&sAh[ar * 40 + ac] = ph;
    *(uint4*)&sBh[ar * 40 + ac] = pb;
    __syncthreads();
    if (kt + 1 < 6) {
      const int k0 = (kt + 1) * 32;
      if (aload) ph = *(const uint4*)(Ah + a_off + k0);
      pb = *(const uint4*)(Bh + b_off + k0);
    }
    const short8 ah = *(const short8*)&sAh[(wm + lm) * 40 + quad * 8];
    const short8 b0 = *(const short8*)&sBh[(wn + lm) * 40 + quad * 8];
    const short8 b1 = *(const short8*)&sBh[(wn + 16 + lm) * 40 + quad * 8];
    acc0 = __builtin_amdgcn_mfma_f32_16x16x32_bf16(ah, b0, acc0, 0, 0, 0);
    acc1 = __builtin_amdgcn_mfma_f32_16x16x32_bf16(ah, b1, acc1, 0, 0, 0);
    __syncthreads();
  }

  const int col = bn + wn + lm;
  const int row0 = bm + wm + quad * 4;
#pragma unroll
  for (int r = 0; r < 4; ++r) {
    C[(size_t)(row0 + r) * 384 + col]      = acc0[r];
    C[(size_t)(row0 + r) * 384 + col + 16] = acc1[r];
  }
}

// ---------------------------------------------------------------------------
// Gates GEMM + fused LSTM. BM=128 x BN=96 (4 gate-strips of 24 j), BK=64.
// 512 thr, 8 waves 4(M)x2(N): wave tile 32x48 (FM=2, FN=3).
// Staging per ktile (28KB): A 1024 chunks = 2 issues x 512thr; B 768 chunks
// = 1 issue x 512 + 1 issue x 256 (waves 0-3: 4 loads, waves 4-7: 3).
// Counted vmcnt(4)/(3) steady, vmcnt(0) last; raw s_barrier pair per ktile.
// Grid 256 = 1 block/CU of 8 waves = 2/SIMD. XCD swizzle: 8 bm x 4 js/XCD.
// ---------------------------------------------------------------------------
__global__ __launch_bounds__(512, 2) void gates_lstm(
    const u16* __restrict__ Ah,   // act rd [B][KPAD]
    const u16* __restrict__ Wh,   // wcat [3072][KPAD], rows = gate*768+j
    const float* __restrict__ bsum,
    float* __restrict__ cst, float* __restrict__ hmax,
    u16* __restrict__ out_h)      // act wr (h section written)
{
  __shared__ __align__(16) char smem[2 * GBUF];   // 57344 B

  const int tid = threadIdx.x, lane = tid & 63, wid = tid >> 6;
  const int wm = (wid >> 1) * 32, wn = (wid & 1) * 48;
  const int lm = lane & 15, quad = lane >> 4;

  // XCD-chunked block swizzle (256 = 8 XCD * 32).
  const int wg = blockIdx.x;
  const int vid = (wg & 7) * 32 + (wg >> 3);
  const int bm = (vid & 7) * 128;         // sample strip (8 strips)
  const int j0 = (vid >> 3) * 24;         // j strip (32 strips of 24)

  // --- staging source pointers (per-lane, swizzle folded into column) ---
  // A: 1024 chunks (128 rows x 8 slots); issue i chunk = i*512 + tid.
  const u16* Asrc[2];
#pragma unroll
  for (int i = 0; i < 2; ++i) {
    const int r = i * 64 + (tid >> 3);
    const int s = (tid & 7) ^ (r & 7);
    Asrc[i] = Ah + (size_t)(bm + r) * KPAD + (s << 3);
  }
  // B: 768 chunks (96 rows x 8 slots); issue0 = tid, issue1 = 512+tid (tid<256)
  const u16* Bsrc0;
  const u16* Bsrc1;
  {
    const int r0 = tid >> 3;
    const int s0 = (tid & 7) ^ (r0 & 7);
    const int nrow0 = (r0 / 24) * HDIM + j0 + (r0 % 24);
    Bsrc0 = Wh + (size_t)nrow0 * KPAD + (s0 << 3);
    const int r1 = 64 + (tid >> 3);
    const int s1 = (tid & 7) ^ (r1 & 7);
    const int r1c = (r1 < 96) ? r1 : 95;               // clamp (unused lanes)
    const int nrow1 = (r1c / 24) * HDIM + j0 + (r1c % 24);
    Bsrc1 = Wh + (size_t)nrow1 * KPAD + (s1 << 3);
  }

  // --- ds_read fragment offsets (halfs); kk toggles slot bit 2 (half-bit 5)
  int aoff[2], boff[3];
#pragma unroll
  for (int mi = 0; mi < 2; ++mi) {
    const int R = wm + mi * 16 + lm;
    aoff[mi] = R * 64 + ((quad ^ (R & 7)) << 3);
  }
#pragma unroll
  for (int ni = 0; ni < 3; ++ni) {
    const int R = wn + ni * 16 + lm;
    boff[ni] = R * 64 + ((quad ^ (R & 7)) << 3);
  }

  f32x4 acc[2][3];
#pragma unroll
  for (int mi = 0; mi < 2; ++mi)
#pragma unroll
    for (int ni = 0; ni < 3; ++ni) acc[mi][ni] = (f32x4){0.f, 0.f, 0.f, 0.f};

  auto stage = [&](int buf, int kt) {
    char* bb = smem + buf * GBUF;
    const int k0 = kt * 64;               // halfs
    gload16(Asrc[0] + k0, bb + (tid << 4));            // A rows 0..63
    gload16(Asrc[1] + k0, bb + 8192 + (tid << 4));     // A rows 64..127
    gload16(Bsrc0 + k0, bb + 16384 + (tid << 4));      // B rows 0..63
    if (tid < 256)
      gload16(Bsrc1 + k0, bb + 24576 + (tid << 4));    // B rows 64..95
  };

  stage(0, 0);                            // waves0-3: 4, waves4-7: 3 in flight

  for (int kt = 0; kt < KT_G; ++kt) {
    if (kt + 1 < KT_G) {
      stage((kt + 1) & 1, kt + 1);        // 8/6 in flight
      if (wid < 4) asm volatile("s_waitcnt vmcnt(4)" ::: "memory");
      else         asm volatile("s_waitcnt vmcnt(3)" ::: "memory");
    } else {
      asm volatile("s_waitcnt vmcnt(0)" ::: "memory");
    }
    asm volatile("s_barrier" ::: "memory");   // all waves' buf[cur] ready

    const u16* sA = (const u16*)(smem + (kt & 1) * GBUF);
    const u16* sB = sA + 8192;            // A is 128x64 halfs = 16KB
#pragma unroll
    for (int kk = 0; kk < 2; ++kk) {
      const int kx = kk << 5;             // toggle half-bit 5 = slot bit 2
      short8 af[2], bg[3];
#pragma unroll
      for (int mi = 0; mi < 2; ++mi)
        af[mi] = *(const short8*)(sA + (aoff[mi] ^ kx));
#pragma unroll
      for (int ni = 0; ni < 3; ++ni)
        bg[ni] = *(const short8*)(sB + (boff[ni] ^ kx));
#pragma unroll
      for (int mi = 0; mi < 2; ++mi)
#pragma unroll
        for (int ni = 0; ni < 3; ++ni)
          acc[mi][ni] = __builtin_amdgcn_mfma_f32_16x16x32_bf16(
              af[mi], bg[ni], acc[mi][ni], 0, 0, 0);
    }
    asm volatile("s_barrier" ::: "memory");   // reads of buf[cur] done
  }

  // ---- epilogue: acc -> 128x100 fp32 LDS tile (col = gate*24 + jj) ----
  float* tile = (float*)smem;               // 51200 B
#pragma unroll
  for (int mi = 0; mi < 2; ++mi)
#pragma unroll
    for (int ni = 0; ni < 3; ++ni) {
      const int c = wn + ni * 16 + lm;
#pragma unroll
      for (int r = 0; r < 4; ++r)
        tile[(wm + mi * 16 + quad * 4 + r) * 100 + c] = acc[mi][ni][r];
    }
  __syncthreads();

#pragma unroll
  for (int i = 0; i < 6; ++i) {
    const int lin = tid + 512 * i;        // 128 rows x 24 jj = 3072
    const int row = lin / 24, jj = lin - row * 24;
    const int b = bm + row, j = j0 + jj;
    const float* tr = tile + row * 100;
    const float pi = tr[jj]      + bsum[j];
    const float pf = tr[24 + jj] + bsum[HDIM + j];
    const float pg = tr[48 + jj] + bsum[2 * HDIM + j];
    const float po = tr[72 + jj] + bsum[3 * HDIM + j];
    const float si = fsigm(pi);
    const float sf = fsigm(pf);
    const float so = fsigm(po);
    const size_t cidx = (size_t)b * HDIM + j;
    const float cn = sf * cst[cidx] + si * ftanh(pg);
    const float hn = so * ftanh(cn);
    cst[cidx] = cn;
    hmax[cidx] = fmaxf(hmax[cidx], hn);
    out_h[(size_t)b * KPAD + VOFF + j] = f2bf(hn);
  }
}

// ---------------------------------------------------------------------------
// softmax_v: logits = sum of 4 split-K partials + b_att; wave-shuffle
// softmax (3 barriers); v = alp @ X via MFMA (9 d-tiles x 4 K-steps, one
// d-tile per wave, wave 0 takes tile 8). alp stored bf16; A rows 3-15 are
// zero fragments; B rows clamped to d=129 (unused lanes discarded).
// ---------------------------------------------------------------------------
__global__ __launch_bounds__(512, 4) void softmax_v(
    const float* __restrict__ lpart,     // [4][B][384]
    const float* __restrict__ b_att,
    const u16* __restrict__ XT,          // [B][130][128] bf16 (linear)
    u16* __restrict__ act)
{
  const int b = blockIdx.x;
  const int t = threadIdx.x;
  __shared__ __align__(16) u16 sXT[XELEM];   // swizzled [130][128]
  __shared__ __align__(16) u16 s_alpb[384];  // alp bf16 [3][128]
  __shared__ float s_w[16];

  {
    const uint4* src = (const uint4*)(XT + (size_t)b * XELEM);
    uint4* dst = (uint4*)sXT;
#pragma unroll
    for (int rep = 0; rep < 4; ++rep) {
      const int i = t + rep * 512;       // 0..2047
      const int d = i >> 4, blk = i & 15;
      dst[d * 16 + (blk ^ (d & 7))] = src[i];
    }
    if (t < 32) {
      const int i = 2048 + t;
      const int d = i >> 4, blk = i & 15;
      dst[d * 16 + (blk ^ (d & 7))] = src[i];
    }
  }

  const int lane = t & 63, wv = t >> 6, hw = wv & ~1;
  float x = -3.4e38f;
  if (t < 384) {
    const size_t str = (size_t)B_SZ * 384;
    const float* lp = lpart + (size_t)b * 384 + t;
    x = b_att[t] + ((lp[0] + lp[str]) + (lp[2 * str] + lp[3 * str]));
  }

  float m = x;
#pragma unroll
  for (int off = 32; off > 0; off >>= 1) m = fmaxf(m, __shfl_xor(m, off));
  if (lane == 0 && wv < 6) s_w[wv] = m;
  __syncthreads();

  float e = 0.f;
  if (t < 384) e = __expf(x - fmaxf(s_w[hw], s_w[hw | 1]));
  float sum = e;
#pragma unroll
  for (int off = 32; off > 0; off >>= 1) sum += __shfl_xor(sum, off);
  if (lane == 0 && wv < 6) s_w[8 + wv] = sum;
  __syncthreads();

  if (t < 384) {
    const float sk = s_w[8 + hw] + s_w[8 + (hw | 1)];
    s_alpb[t] = f2bf(e * frcp(sk));
  }
  __syncthreads();    // orders sXT staging + s_alpb for the v phase

  // ---- v = alp @ X via MFMA: wave wv does d-tile wv (+ tile 8 on wave 0) --
  {
    const int lmn = lane & 15, qd = lane >> 4;
    for (int tile = wv; tile < 9; tile += 8) {
      const int d0 = tile * 16;
      const int dr = (d0 + lmn < DIN) ? (d0 + lmn) : (DIN - 1);  // clamp B row
      f32x4 vacc = {0.f, 0.f, 0.f, 0.f};
#pragma unroll
      for (int kk = 0; kk < 4; ++kk) {
        short8 afr = (short8){0, 0, 0, 0, 0, 0, 0, 0};
        if (lmn < 3)
          afr = *(const short8*)&s_alpb[lmn * 128 + kk * 32 + qd * 8];
        const int ch = (kk * 4 + qd) ^ (dr & 7);
        const short8 bfr = *(const short8*)&sXT[(dr * 16 + ch) * 8];
        vacc = __builtin_amdgcn_mfma_f32_16x16x32_bf16(afr, bfr, vacc, 0, 0, 0);
      }
      if (qd == 0) {
        const int d = d0 + lmn;
        if (d < DIN) {
#pragma unroll
          for (int r = 0; r < 3; ++r)
            act[(size_t)b * KPAD + r * DIN + d] = f2bf(vacc[r]);
        }
      }
    }
  }
}

// ---------------------------------------------------------------------------
// Final head (once per call).
// ---------------------------------------------------------------------------
__global__ __launch_bounds__(64) void final_head(
    const float* __restrict__ hmax, const float* __restrict__ Fe,
    const float* __restrict__ W_d1, const float* __restrict__ b_d1,
    const float* __restrict__ W_r,  const float* __restrict__ b_r,
    const float* __restrict__ W_a,
    const float* __restrict__ W_d2, const float* __restrict__ b_d2,
    float* __restrict__ out)
{
  const int b = blockIdx.x;
  const int t = threadIdx.x;
  __shared__ float sx[HDIM];
  __shared__ float sy[NFEAT];
  __shared__ float sr1[NPROJ], sr2[NPROJ];
  __shared__ float sa[2];

  for (int i = t; i < HDIM; i += 64) sx[i] = hmax[(size_t)b * HDIM + i];
  __syncthreads();

  if (t < NFEAT) {
    float acc = b_d1[t];
    const float* w = W_d1 + (size_t)t * HDIM;
    for (int i = 0; i < HDIM; ++i) acc += sx[i] * w[i];
    sy[t] = fmaxf(acc, 0.f);
  }
  __syncthreads();

  if (t < NPROJ) {
    float a1 = b_r[t], a2 = b_r[t];
    const float* w  = W_r + (size_t)t * NFEAT;
    const float* fe = Fe + (size_t)b * NFEAT;
    for (int i = 0; i < NFEAT; ++i) { a1 += sy[i] * w[i]; a2 += fe[i] * w[i]; }
    sr1[t] = (a1 > 0.f) ? a1 : 0.01f * a1;
    sr2[t] = (a2 > 0.f) ? a2 : 0.01f * a2;
  }
  __syncthreads();

  if (t == 0) {
    float a1 = 0.f, a2 = 0.f;
    for (int p = 0; p < NPROJ; ++p) {
      a1 += tanhf(sr1[p]) * W_a[p];
      a2 += tanhf(sr2[p]) * W_a[p];
    }
    const float mx = fmaxf(a1, a2);
    const float e1 = expf(a1 - mx), e2 = expf(a2 - mx);
    sa[0] = e1 / (e1 + e2);
    sa[1] = e2 / (e1 + e2);
  }
  __syncthreads();

  if (t < 2) {
    float acc = b_d2[t];
    const float* w = W_d2 + (size_t)t * NPROJ;
    for (int p = 0; p < NPROJ; ++p) {
      float s = sa[0] * sr1[p] + sa[1] * sr2[p];
      s = fmaxf(s, 0.f);
      acc += s * w[p];
    }
    out[(size_t)b * 2 + t] = acc;
  }
}

// ---------------------------------------------------------------------------
// Setup kernels (run every launch).
// ---------------------------------------------------------------------------
__global__ __launch_bounds__(256) void pack_w(
    const float* __restrict__ W_ih, const float* __restrict__ W_hh,
    const float* __restrict__ b_ih, const float* __restrict__ b_hh,
    u16* __restrict__ hi, float* __restrict__ bsum)
{
  const int idx = blockIdx.x * 256 + threadIdx.x;
  if (idx >= NGATE * KPAD) return;
  const int n = idx / KPAD;
  const int k = idx - n * KPAD;
  float v = 0.f;
  if (k < 3 * DIN)                       v = W_ih[(size_t)n * (3 * DIN) + k];
  else if (k >= VOFF && k < VOFF + HDIM) v = W_hh[(size_t)n * HDIM + (k - VOFF)];
  hi[idx] = f2bf(v);
  if (k == 0) bsum[n] = b_ih[n] + b_hh[n];
}

__global__ __launch_bounds__(256) void pack_watt(
    const float* __restrict__ W_att,   // [3][H][L]
    u16* __restrict__ hi)
{
  const int idx = blockIdx.x * 256 + threadIdx.x;   // [384][768]
  if (idx >= 384 * HDIM) return;
  const int n = idx / HDIM;          // n = k*128 + l
  const int h = idx - n * HDIM;
  const int katt = n >> 7;
  const int l = n & 127;
  hi[idx] = f2bf(W_att[((size_t)katt * HDIM + h) * LSEQ + l]);
}

// X[b][l][d] fp32 -> XT[b][d][l] bf16 (linear). One block/sample, LDS bounce.
__global__ __launch_bounds__(256) void pack_xt(
    const float* __restrict__ X, u16* __restrict__ XT)
{
  const int b = blockIdx.x;
  const int t = threadIdx.x;
  __shared__ u16 sX[XELEM];   // [l][d]
  const float* src = X + (size_t)b * XELEM;
  for (int i = t; i < XELEM; i += 256) sX[i] = f2bf(src[i]);
  __syncthreads();
  uint4* dst = (uint4*)(XT + (size_t)b * XELEM);
  for (int u = t; u < 2080; u += 256) {    // uint4 index = d*16 + blk
    const int d = u >> 4, blk = u & 15;
    const int lb = blk * 8;
    ushort4 w0, w1;
    w0.x = sX[(lb + 0) * DIN + d]; w0.y = sX[(lb + 1) * DIN + d];
    w0.z = sX[(lb + 2) * DIN + d]; w0.w = sX[(lb + 3) * DIN + d];
    w1.x = sX[(lb + 4) * DIN + d]; w1.y = sX[(lb + 5) * DIN + d];
    w1.z = sX[(lb + 6) * DIN + d]; w1.w = sX[(lb + 7) * DIN + d];
    uint4 o;
    o.x = (unsigned)w0.x | ((unsigned)w0.y << 16);
    o.y = (unsigned)w0.z | ((unsigned)w0.w << 16);
    o.z = (unsigned)w1.x | ((unsigned)w1.y << 16);
    o.w = (unsigned)w1.z | ((unsigned)w1.w << 16);
    dst[u] = o;
  }
}

__global__ __launch_bounds__(256) void init_state(
    u16* __restrict__ a0, u16* __restrict__ a1,
    float* __restrict__ cst, float* __restrict__ hmax)
{
  const int idx = blockIdx.x * 256 + threadIdx.x;
  if (idx < B_SZ * KPAD) { a0[idx] = 0; a1[idx] = 0; }
  if (idx < B_SZ * HDIM) { cst[idx] = 0.f; hmax[idx] = -3.4e38f; }
}

// ---------------------------------------------------------------------------
extern "C" void kernel_launch(void* const* d_in, const int* in_sizes, int n_in,
                              void* d_out, int out_size, void* d_ws, size_t ws_size,
                              hipStream_t stream) {
  const float* X     = (const float*)d_in[0];
  const float* Fe    = (const float*)d_in[1];
  const float* W_att = (const float*)d_in[2];
  const float* b_att = (const float*)d_in[3];
  const float* W_ih  = (const float*)d_in[4];
  const float* W_hh  = (const float*)d_in[5];
  const float* b_ih  = (const float*)d_in[6];
  const float* b_hh  = (const float*)d_in[7];
  const float* W_d1  = (const float*)d_in[8];
  const float* b_d1  = (const float*)d_in[9];
  const float* W_r   = (const float*)d_in[10];
  const float* b_r   = (const float*)d_in[11];
  const float* W_a   = (const float*)d_in[12];
  const float* W_d2  = (const float*)d_in[13];
  const float* b_d2  = (const float*)d_in[14];
  float* out = (float*)d_out;

  char* base = (char*)d_ws;
  size_t off = 0;
  auto alloc = [&](size_t nbytes) -> void* {
    void* p = base + off;
    off = (off + nbytes + 255) & ~(size_t)255;
    return p;
  };
  u16* act0    = (u16*)alloc((size_t)B_SZ * KPAD * 2);
  u16* act1    = (u16*)alloc((size_t)B_SZ * KPAD * 2);
  u16* wcat    = (u16*)alloc((size_t)NGATE * KPAD * 2);
  u16* watt    = (u16*)alloc((size_t)384 * HDIM * 2);
  u16* xt16    = (u16*)alloc((size_t)B_SZ * XELEM * 2);
  float* bsum  = (float*)alloc((size_t)NGATE * 4);
  float* lpart = (float*)alloc((size_t)4 * B_SZ * 384 * 4);
  float* cst   = (float*)alloc((size_t)B_SZ * HDIM * 4);
  float* hmax  = (float*)alloc((size_t)B_SZ * HDIM * 4);

  pack_w<<<(NGATE * KPAD + 255) / 256, 256, 0, stream>>>(W_ih, W_hh, b_ih, b_hh, wcat, bsum);
  pack_watt<<<(384 * HDIM + 255) / 256, 256, 0, stream>>>(W_att, watt);
  pack_xt<<<B_SZ, 256, 0, stream>>>(X, xt16);
  init_state<<<(B_SZ * KPAD + 255) / 256, 256, 0, stream>>>(act0, act1, cst, hmax);

  // step-0 attention on h=0 (logits = b_att): partials from zero h are zero
  gemm_logits_k<<<dim3(B_SZ / 32, 384 / 64, 4), 256, 0, stream>>>(act0 + VOFF, watt, lpart);
  softmax_v<<<B_SZ, 512, 0, stream>>>(lpart, b_att, xt16, act0);

  u16 *rd = act0, *wr = act1;
  for (int step = 0; step < LSEQ; ++step) {
    gates_lstm<<<dim3(256), 512, 0, stream>>>(rd, wcat, bsum, cst, hmax, wr);
    if (step + 1 < LSEQ) {
      gemm_logits_k<<<dim3(B_SZ / 32, 384 / 64, 4), 256, 0, stream>>>(wr + VOFF, watt, lpart);
      softmax_v<<<B_SZ, 512, 0, stream>>>(lpart, b_att, xt16, wr);
    }
    u16* tt = rd; rd = wr; wr = tt;
  }

  final_head<<<B_SZ, 64, 0, stream>>>(hmax, Fe, W_d1, b_d1, W_r, b_r, W_a, W_d2, b_d2, out);
}